// Round 4
// baseline (408.093 us; speedup 1.0000x reference)
//
#include <hip/hip_runtime.h>
#include <stdint.h>

// Problem constants
#define B_    8
#define CIN   1024
#define H_    64
#define W_    48
#define OC    512
#define HW    3072          // H*W
#define NPOS  24576         // B*H*W
#define K9    9216          // 9*CIN
#define HP    66            // H+2
#define WP    50            // W+2

typedef __attribute__((ext_vector_type(8))) __bf16 bf16x8;
typedef __attribute__((ext_vector_type(4))) float  float4_t;
typedef __attribute__((ext_vector_type(4))) unsigned short ushort4_t;
typedef __attribute__((ext_vector_type(8))) int int8v;
typedef __attribute__((ext_vector_type(4))) int int4v;

__device__ __forceinline__ unsigned short f2bf(float x) {
  union { float f; unsigned u; } v; v.f = x;
  unsigned r = v.u + 0x7FFFu + ((v.u >> 16) & 1u);
  return (unsigned short)(r >> 16);
}

// pack 4 floats -> 4 fp8 e4m3 bytes (RNE, saturating)
__device__ __forceinline__ unsigned int pack4_fp8(float a, float b, float c, float d) {
  int w = __builtin_amdgcn_cvt_pk_fp8_f32(a, b, 0, false);   // bytes 0,1
  w = __builtin_amdgcn_cvt_pk_fp8_f32(c, d, w, true);        // bytes 2,3
  return (unsigned int)w;
}

__device__ __forceinline__ void async16(const void* g, void* l) {
  __builtin_amdgcn_global_load_lds(
      (const __attribute__((address_space(1))) unsigned int*)g,
      (__attribute__((address_space(3))) unsigned int*)l, 16, 0, 0);
}

__device__ __forceinline__ float wave_sum(float v) {
  for (int o = 32; o > 0; o >>= 1) v += __shfl_down(v, o, 64);
  return v;
}

// ================= fused prep: prep_x | prep_w | prep_wh | borders ======================
// grid = 4096 (prep_x) + 512 (prep_w) + 32 (prep_wh) + 528 (borders) = 5168, 256 threads
__global__ void prep_fused(const float* __restrict__ x, const float* __restrict__ Wc,
                           const float* __restrict__ Wcls, const float* __restrict__ Wbb,
                           unsigned char* __restrict__ xt, unsigned char* __restrict__ Wa,
                           unsigned short* __restrict__ Wh, float* __restrict__ accbuf) {
  __shared__ float smem[9216];   // 36 KB shared across branches
  int bid = blockIdx.x, t = threadIdx.x;
  if (bid < 4096) {
    // ---- prep_x: pad+transpose NCHW fp32 -> NHWC fp8 (x16), one (b,h,128c) slice ----
    int cx = bid & 7, h = (bid >> 3) & 63, b = bid >> 9;
    float* tile = smem;   // [128][49]
    const float* src = x + ((long)(b * CIN + cx * 128) * H_ + h) * W_;
    for (int it = 0; it < 6; ++it) {
      int e = it * 256 + t;
      int cl = e / 12, w4 = e % 12;
      float4_t v = *(const float4_t*)&src[(long)cl * HW + w4 * 4];
      int base = cl * 49 + w4 * 4;
      tile[base] = v.x; tile[base + 1] = v.y; tile[base + 2] = v.z; tile[base + 3] = v.w;
    }
    __syncthreads();
    unsigned char* dst = xt + ((long)(b * HP + h + 1) * WP + 1) * CIN + cx * 128;
    for (int it = 0; it < 6; ++it) {
      int e = it * 256 + t;
      int w = e >> 5, g = e & 31;
      float v0 = tile[(g * 4 + 0) * 49 + w] * 16.f;
      float v1 = tile[(g * 4 + 1) * 49 + w] * 16.f;
      float v2 = tile[(g * 4 + 2) * 49 + w] * 16.f;
      float v3 = tile[(g * 4 + 3) * 49 + w] * 16.f;
      *(unsigned int*)&dst[(long)w * CIN + g * 4] = pack4_fp8(v0, v1, v2, v3);
    }
  } else if (bid < 4608) {
    // ---- prep_w: W_conv [512,1024,3,3] -> Wa [512,9216] fp8 (x512), k=(off*1024+c) ----
    int o = bid - 4096;
    float* lw = smem;   // [9216]
    const float* src = Wc + (long)o * K9;
    for (int i = 0; i < 9; ++i)
      *(float4_t*)&lw[i * 1024 + t * 4] = *(const float4_t*)&src[i * 1024 + t * 4];
    __syncthreads();
    unsigned char* dst = Wa + (long)o * K9;
    int c = t * 4;
    for (int off = 0; off < 9; ++off) {
      float v0 = lw[(c + 0) * 9 + off] * 512.f;
      float v1 = lw[(c + 1) * 9 + off] * 512.f;
      float v2 = lw[(c + 2) * 9 + off] * 512.f;
      float v3 = lw[(c + 3) * 9 + off] * 512.f;
      *(unsigned int*)&dst[off * 1024 + c] = pack4_fp8(v0, v1, v2, v3);
    }
  } else if (bid < 4640) {
    // ---- prep_wh: head weights -> Wh [64,512] bf16 (rows 54..63 zero) ----
    int e = (bid - 4608) * 1024 + t * 4;
    int m = e >> 9, c = e & 511;
    float v0 = 0.f, v1 = 0.f, v2 = 0.f, v3 = 0.f;
    if (m < 18) {
      const float* s = Wcls + m * 512 + c;
      v0 = s[0]; v1 = s[1]; v2 = s[2]; v3 = s[3];
    } else if (m < 54) {
      const float* s = Wbb + (m - 18) * 512 + c;
      v0 = s[0]; v1 = s[1]; v2 = s[2]; v3 = s[3];
    }
    ushort4_t pk; pk.x = f2bf(v0); pk.y = f2bf(v1); pk.z = f2bf(v2); pk.w = f2bf(v3);
    *(ushort4_t*)&Wh[e] = pk;
    if (bid == 4608 && t < 4) accbuf[t] = 0.f;
  } else {
    // ---- borders: zero-pad halo of xt ----
    int bid2 = bid - 4640;
    int b = bid2 / 66, h = bid2 % 66;
    unsigned char* base = xt + (long)(b * 66 + h) * 50 * 1024;
    int4v z = {};
    if (h == 0 || h == 65) {
      for (int i = t; i < 3200; i += 256) *(int4v*)(base + (long)i * 16) = z;
    } else if (t < 128) {
      int which = t >> 6, off = t & 63;
      *(int4v*)(base + (long)which * 49 * 1024 + (long)off * 16) = z;
    }
  }
}

// ---------------- main conv GEMM (MX-fp8): M=512, N=24576, K=9216 ------------------------
// v4b: tile 128(M) x 192(N), BK=128. grid (128,4) = 512 blocks = exactly 2/CU (no tail).
// A (weights) bypasses LDS: per-lane fragment loads global->VGPR (single-set, snapshot
// to af then reload k+1; compiler inserts the minimal vmcnt at the snapshot). A's kt-window
// is 64 KB shared by all 512 blocks -> L2/L3-hot. Cuts LDS traffic 40% and A-read conflicts.
// B: LDS double-buffer 2x24 KB = 48 KB, counted-vmcnt acquire (14 = A(k)8 + B(k+1)6 in
// flight), lgkmcnt(0) release. Never vmcnt(0) in steady state.
__global__ __launch_bounds__(256, 2)
void conv_gemm(const unsigned char* __restrict__ Wa, const unsigned char* __restrict__ xt,
               const float* __restrict__ bias, unsigned short* __restrict__ conv1) {
  __shared__ unsigned char Bs_[2][192 * 128];     // 2 x 24 KB
  int t = threadIdx.x;
  int lane = t & 63, wv = t >> 6;
  int m0 = blockIdx.y * 128;
  int n0 = blockIdx.x * 192;
  int wm = wv >> 1, wn = wv & 1;
  int quad = lane >> 4, col = lane & 15;
  const unsigned char* bSrc[6];
  for (int p = 0; p < 6; ++p) {
    int c = p * 256 + t;
    int r = c >> 3;
    int q = (c & 7) ^ (r & 7);
    int n = n0 + r; int b = n / HW; int rem = n % HW; int h = rem / W_; int w = rem % W_;
    bSrc[p] = xt + ((long)(b * HP + h) * WP + w) * CIN + q * 16;
  }
  // per-lane A fragment base: row = m0 + wm*64 + i*16 + (lane&15), kbyte = (lane>>4)*32
  // (exact mfma_scale 16x16x128 fp8 A layout — same mapping the LDS path used)
  const unsigned char* aBase[4];
  for (int i = 0; i < 4; ++i)
    aBase[i] = Wa + (long)(m0 + wm * 64 + i * 16 + col) * K9 + quad * 32;

  float4_t acc[4][6] = {};

  auto stageB = [&](int buf, int kt) {
    int off = kt >> 3;                       // which of the 9 (dy,dx) taps
    int dy = off / 3, dx = off % 3;
    long boff = (long)(dy * WP + dx) * CIN + (kt & 7) * 128;
    for (int p = 0; p < 6; ++p)
      async16(bSrc[p] + boff, &Bs_[buf][p * 4096 + wv * 1024]);
  };

  // prologue: B(0) staged FIRST, then A(0) loads (issue order defines vmcnt counting)
  stageB(0, 0);
  __builtin_amdgcn_sched_barrier(0);
  int4v aLo[4], aHi[4];
  for (int i = 0; i < 4; ++i) {
    aLo[i] = *(const int4v*)(aBase[i]);
    aHi[i] = *(const int4v*)(aBase[i] + 16);
  }
  __builtin_amdgcn_sched_barrier(0);

#pragma unroll 1
  for (int kt = 0; kt < 72; ++kt) {
    if (kt + 1 < 72) {
      stageB((kt + 1) & 1, kt + 1);
      // outstanding: B(kt)[6] < A(kt)[8] < B(kt+1)[6]; drain oldest 6 = B(kt) landed
      asm volatile("s_waitcnt vmcnt(14)\n\ts_barrier" ::: "memory");
    } else {
      // outstanding: B(71)[6] < A(71)[8]; drain oldest 6 = B(71) landed
      asm volatile("s_waitcnt vmcnt(8)\n\ts_barrier" ::: "memory");
    }
    __builtin_amdgcn_sched_barrier(0);
    const unsigned char* Bcur = Bs_[kt & 1];
    int8v bfr[6];
    for (int j = 0; j < 6; ++j) {
      int r = wn * 96 + j * 16 + col;
      int rb = r * 128, x7 = r & 7;
      int4v lo = *(const int4v*)&Bcur[rb + (((quad * 2 + 0) ^ x7) << 4)];
      int4v hi = *(const int4v*)&Bcur[rb + (((quad * 2 + 1) ^ x7) << 4)];
      bfr[j] = (int8v){lo.x, lo.y, lo.z, lo.w, hi.x, hi.y, hi.z, hi.w};
    }
    // release: all waves' LDS reads of B(kt) complete -> buffer free for restage next step
    asm volatile("s_waitcnt lgkmcnt(0)\n\ts_barrier" ::: "memory");
    __builtin_amdgcn_sched_barrier(0);
    // snapshot A(kt) into af (compiler auto-inserts vmcnt(6): waits A(kt), leaves B(kt+1)
    // in flight), then immediately issue A(kt+1) — lands under the 24-MFMA cluster.
    int8v af[4];
    for (int i = 0; i < 4; ++i)
      af[i] = (int8v){aLo[i].x, aLo[i].y, aLo[i].z, aLo[i].w,
                      aHi[i].x, aHi[i].y, aHi[i].z, aHi[i].w};
    // prefetch A(kt+1); last iteration wraps to offset 0 (values discarded) to stay
    // strictly inside Wa
    long ko = (kt + 1 < 72) ? (long)(kt + 1) * 128 : 0;
    for (int i = 0; i < 4; ++i) {
      aLo[i] = *(const int4v*)(aBase[i] + ko);
      aHi[i] = *(const int4v*)(aBase[i] + ko + 16);
    }
    __builtin_amdgcn_sched_barrier(0);
    __builtin_amdgcn_s_setprio(1);
    for (int i = 0; i < 4; ++i)
      for (int j = 0; j < 6; ++j)
        // A=W scaled by 2^9 -> e8m0 118 (2^-9); B=x scaled by 2^4 -> e8m0 123 (2^-4)
        acc[i][j] = __builtin_amdgcn_mfma_scale_f32_16x16x128_f8f6f4(
            af[i], bfr[j], acc[i][j], 0, 0, 0, 0x76767676, 0, 0x7B7B7B7B);
    __builtin_amdgcn_s_setprio(0);
    __builtin_amdgcn_sched_barrier(0);
  }

  // epilogue: bias + relu, store bf16 conv1[n*512 + m], 8B packed along m
  for (int i = 0; i < 4; ++i) {
    int mb = m0 + wm * 64 + i * 16 + quad * 4;
    float b0 = bias[mb + 0], b1 = bias[mb + 1], b2 = bias[mb + 2], b3 = bias[mb + 3];
    for (int j = 0; j < 6; ++j) {
      int n = n0 + wn * 96 + j * 16 + col;
      ushort4_t pk;
      pk.x = f2bf(fmaxf(acc[i][j].x + b0, 0.f));
      pk.y = f2bf(fmaxf(acc[i][j].y + b1, 0.f));
      pk.z = f2bf(fmaxf(acc[i][j].z + b2, 0.f));
      pk.w = f2bf(fmaxf(acc[i][j].w + b3, 0.f));
      *(ushort4_t*)&conv1[(long)n * 512 + mb] = pk;
    }
  }
}

// ---------------- head GEMM: [64 x 512] @ conv1^T -> cls_score (ws) + bbox_pred (d_out) --
// M=64 (54 used), N=24576, K=512. Tile 64(N) x BK=128. grid 384, 256 threads.
// 16B-chunk xor swizzle (16 chunks/row): phys = q ^ (r&15)
__global__ __launch_bounds__(256, 2)
void head_gemm(const unsigned short* __restrict__ Wh, const unsigned short* __restrict__ conv1,
               const float* __restrict__ b_cls, const float* __restrict__ b_bbox,
               float* __restrict__ cls_ws, float* __restrict__ out_bbox) {
  __shared__ unsigned short As[64 * 128];   // 16 KB
  __shared__ unsigned short Bs[64 * 128];   // 16 KB
  int t = threadIdx.x;
  int lane = t & 63, wv = t >> 6;
  int n0 = blockIdx.x * 64;
  int quad = lane >> 4, col = lane & 15;
  const unsigned short* aS[4];
  const unsigned short* bS[4];
  for (int p = 0; p < 4; ++p) {
    int c = p * 256 + t;
    int r = c >> 4;
    int q = (c & 15) ^ (r & 15);
    aS[p] = Wh + (long)r * 512 + q * 8;
    bS[p] = conv1 + (long)(n0 + r) * 512 + q * 8;
  }
  float4_t acc[4] = {};
  for (int kt = 0; kt < 4; ++kt) {
    long koff = (long)kt * 128;
    __syncthreads();
    for (int p = 0; p < 4; ++p) async16(aS[p] + koff, &As[p * 2048 + wv * 512]);
    for (int p = 0; p < 4; ++p) async16(bS[p] + koff, &Bs[p * 2048 + wv * 512]);
    __syncthreads();
    for (int ks = 0; ks < 4; ++ks) {
      int rn = wv * 16 + col;
      bf16x8 bfr = *(const bf16x8*)&Bs[rn * 128 + (((ks * 4 + quad) ^ (rn & 15)) << 3)];
      for (int i = 0; i < 4; ++i) {
        int r = i * 16 + col;
        bf16x8 af = *(const bf16x8*)&As[r * 128 + (((ks * 4 + quad) ^ (r & 15)) << 3)];
        acc[i] = __builtin_amdgcn_mfma_f32_16x16x32_bf16(af, bfr, acc[i], 0, 0, 0);
      }
    }
  }
  int n = n0 + wv * 16 + col;
  int b = n / HW; int rem = n % HW;   // rem = h*48 + w
  for (int i = 0; i < 4; ++i) {
    for (int r = 0; r < 4; ++r) {
      int m = i * 16 + quad * 4 + r;
      float v = acc[i][r];
      if (m < 18) {
        cls_ws[(long)(b * 18 + m) * HW + rem] = v + b_cls[m];
      } else if (m < 54) {
        out_bbox[(long)(b * 36 + (m - 18)) * HW + rem] = v + b_bbox[m - 18];
      }
    }
  }
}

// ---------------- fused losses: softmax+NLL (blocks 0..863) | smooth-L1 box (864..2591) --
__global__ void loss_fused(const float* __restrict__ cls, const int* __restrict__ label,
                           float* __restrict__ prob,
                           const float* __restrict__ pred, const float* __restrict__ tgt,
                           const float* __restrict__ iw, const float* __restrict__ ow,
                           float* __restrict__ acc) {
  int lane = threadIdx.x & 63, wv = threadIdx.x >> 6;
  __shared__ float red[8];
  if (blockIdx.x < 864) {
    int idx = blockIdx.x * 256 + threadIdx.x;
    int b = idx / 27648; int r = idx % 27648;
    int a = r / HW; int r2 = r % HW;
    long i0 = (long)(b * 18 + a) * HW + r2;
    long i1 = i0 + (long)9 * HW;
    float x0 = cls[i0], x1 = cls[i1];
    float mx = fmaxf(x0, x1);
    float e0 = __expf(x0 - mx), e1 = __expf(x1 - mx);
    float s = e0 + e1;
    prob[i0] = e0 / s;
    prob[i1] = e1 / s;
    int lb = label[idx];
    float nll = 0.f, val = 0.f;
    if (lb != -1) {
      val = 1.f;
      float xl = (lb > 0) ? x1 : x0;
      nll = -(xl - mx - __logf(s));
    }
    nll = wave_sum(nll);
    val = wave_sum(val);
    if (lane == 0) { red[wv] = nll; red[4 + wv] = val; }
    __syncthreads();
    if (threadIdx.x == 0) {
      atomicAdd(&acc[0], red[0] + red[1] + red[2] + red[3]);
      atomicAdd(&acc[1], red[4] + red[5] + red[6] + red[7]);
    }
  } else {
    int bid = blockIdx.x - 864;
    float s = 0.f;
    const long total = (long)B_ * 36 * HW;   // 884736
    for (long i = (long)bid * 256 + threadIdx.x; i < total; i += (long)1728 * 256) {
      float d = iw[i] * (pred[i] - tgt[i]);
      float ad = fabsf(d);
      float l = (ad < (1.f / 9.f)) ? d * d * 4.5f : ad - (1.f / 18.f);
      s += ow[i] * l;
    }
    s = wave_sum(s);
    if (lane == 0) red[wv] = s;
    __syncthreads();
    if (threadIdx.x == 0) atomicAdd(&acc[2], red[0] + red[1] + red[2] + red[3]);
  }
}

__global__ void finalize(const float* __restrict__ acc, float* __restrict__ out) {
  if (threadIdx.x == 0) {
    out[0] = acc[0] / fmaxf(acc[1], 1.f);
    out[1] = acc[2] / (float)B_;
  }
}

extern "C" void kernel_launch(void* const* d_in, const int* in_sizes, int n_in,
                              void* d_out, int out_size, void* d_ws, size_t ws_size,
                              hipStream_t stream) {
  const float* base_feat = (const float*)d_in[0];
  const float* W_conv    = (const float*)d_in[1];
  const float* b_conv    = (const float*)d_in[2];
  const float* W_cls     = (const float*)d_in[3];
  const float* b_cls     = (const float*)d_in[4];
  const float* W_bbox    = (const float*)d_in[5];
  const float* b_bbox    = (const float*)d_in[6];
  const int*   rpn_label = (const int*)d_in[7];
  const float* bb_tgt    = (const float*)d_in[8];
  const float* bb_iw     = (const float*)d_in[9];
  const float* bb_ow     = (const float*)d_in[10];

  float* out = (float*)d_out;
  float* out_cls_prob = out;                         // 442368
  float* out_bbox     = out + 442368;                // 884736
  float* out_scalars  = out + 442368 + 884736;       // 2

  // workspace layout
  size_t off = 0;
  auto alloc = [&](size_t bytes) {
    void* p = (char*)d_ws + off;
    off = (off + bytes + 255) & ~(size_t)255;
    return p;
  };
  const size_t XT_BYTES = (size_t)B_ * HP * WP * CIN;              // 27,033,600 (fp8)
  unsigned char*  xt    = (unsigned char*)alloc(XT_BYTES);
  unsigned char*  Wa    = (unsigned char*)alloc((size_t)OC * K9);
  unsigned short* conv1 = (unsigned short*)alloc((size_t)NPOS * OC * 2);
  unsigned short* Wh    = (unsigned short*)alloc((size_t)64 * 512 * 2);
  float* cls_ws         = (float*)alloc((size_t)B_ * 18 * HW * 4);
  float* accbuf         = (float*)alloc(16);

  prep_fused<<<5168, 256, 0, stream>>>(base_feat, W_conv, W_cls, W_bbox, xt, Wa, Wh, accbuf);
  conv_gemm<<<dim3(128, 4), 256, 0, stream>>>(Wa, xt, b_conv, conv1);
  head_gemm<<<384, 256, 0, stream>>>(Wh, conv1, b_cls, b_bbox, cls_ws, out_bbox);
  loss_fused<<<2592, 256, 0, stream>>>(cls_ws, rpn_label, out_cls_prob,
                                       out_bbox, bb_tgt, bb_iw, bb_ow, accbuf);
  finalize<<<1, 64, 0, stream>>>(accbuf, out_scalars);
}

// Round 5
// 370.260 us; speedup vs baseline: 1.1022x; 1.1022x over previous
//
#include <hip/hip_runtime.h>
#include <stdint.h>

// Problem constants
#define B_    8
#define CIN   1024
#define H_    64
#define W_    48
#define OC    512
#define HW    3072          // H*W
#define NPOS  24576         // B*H*W
#define K9    9216          // 9*CIN
#define HP    66            // H+2
#define WP    50            // W+2

typedef __attribute__((ext_vector_type(8))) __bf16 bf16x8;
typedef __attribute__((ext_vector_type(4))) float  float4_t;
typedef __attribute__((ext_vector_type(4))) unsigned short ushort4_t;
typedef __attribute__((ext_vector_type(8))) int int8v;
typedef __attribute__((ext_vector_type(4))) int int4v;

__device__ __forceinline__ unsigned short f2bf(float x) {
  union { float f; unsigned u; } v; v.f = x;
  unsigned r = v.u + 0x7FFFu + ((v.u >> 16) & 1u);
  return (unsigned short)(r >> 16);
}

// pack 4 floats -> 4 fp8 e4m3 bytes (RNE, saturating)
__device__ __forceinline__ unsigned int pack4_fp8(float a, float b, float c, float d) {
  int w = __builtin_amdgcn_cvt_pk_fp8_f32(a, b, 0, false);   // bytes 0,1
  w = __builtin_amdgcn_cvt_pk_fp8_f32(c, d, w, true);        // bytes 2,3
  return (unsigned int)w;
}

__device__ __forceinline__ void async16(const void* g, void* l) {
  __builtin_amdgcn_global_load_lds(
      (const __attribute__((address_space(1))) unsigned int*)g,
      (__attribute__((address_space(3))) unsigned int*)l, 16, 0, 0);
}

__device__ __forceinline__ float wave_sum(float v) {
  for (int o = 32; o > 0; o >>= 1) v += __shfl_down(v, o, 64);
  return v;
}

// ================= fused prep: prep_x | prep_w | prep_wh | borders ======================
// grid = 4096 (prep_x) + 512 (prep_w) + 32 (prep_wh) + 528 (borders) = 5168, 256 threads
__global__ void prep_fused(const float* __restrict__ x, const float* __restrict__ Wc,
                           const float* __restrict__ Wcls, const float* __restrict__ Wbb,
                           unsigned char* __restrict__ xt, unsigned char* __restrict__ Wa,
                           unsigned short* __restrict__ Wh, float* __restrict__ accbuf) {
  __shared__ float smem[9216];   // 36 KB shared across branches
  int bid = blockIdx.x, t = threadIdx.x;
  if (bid < 4096) {
    // ---- prep_x: pad+transpose NCHW fp32 -> NHWC fp8 (x16), one (b,h,128c) slice ----
    int cx = bid & 7, h = (bid >> 3) & 63, b = bid >> 9;
    float* tile = smem;   // [128][49]
    const float* src = x + ((long)(b * CIN + cx * 128) * H_ + h) * W_;
    for (int it = 0; it < 6; ++it) {
      int e = it * 256 + t;
      int cl = e / 12, w4 = e % 12;
      float4_t v = *(const float4_t*)&src[(long)cl * HW + w4 * 4];
      int base = cl * 49 + w4 * 4;
      tile[base] = v.x; tile[base + 1] = v.y; tile[base + 2] = v.z; tile[base + 3] = v.w;
    }
    __syncthreads();
    unsigned char* dst = xt + ((long)(b * HP + h + 1) * WP + 1) * CIN + cx * 128;
    for (int it = 0; it < 6; ++it) {
      int e = it * 256 + t;
      int w = e >> 5, g = e & 31;
      float v0 = tile[(g * 4 + 0) * 49 + w] * 16.f;
      float v1 = tile[(g * 4 + 1) * 49 + w] * 16.f;
      float v2 = tile[(g * 4 + 2) * 49 + w] * 16.f;
      float v3 = tile[(g * 4 + 3) * 49 + w] * 16.f;
      *(unsigned int*)&dst[(long)w * CIN + g * 4] = pack4_fp8(v0, v1, v2, v3);
    }
  } else if (bid < 4608) {
    // ---- prep_w: W_conv [512,1024,3,3] -> Wa [512,9216] fp8 (x512), k=(off*1024+c) ----
    int o = bid - 4096;
    float* lw = smem;   // [9216]
    const float* src = Wc + (long)o * K9;
    for (int i = 0; i < 9; ++i)
      *(float4_t*)&lw[i * 1024 + t * 4] = *(const float4_t*)&src[i * 1024 + t * 4];
    __syncthreads();
    unsigned char* dst = Wa + (long)o * K9;
    int c = t * 4;
    for (int off = 0; off < 9; ++off) {
      float v0 = lw[(c + 0) * 9 + off] * 512.f;
      float v1 = lw[(c + 1) * 9 + off] * 512.f;
      float v2 = lw[(c + 2) * 9 + off] * 512.f;
      float v3 = lw[(c + 3) * 9 + off] * 512.f;
      *(unsigned int*)&dst[off * 1024 + c] = pack4_fp8(v0, v1, v2, v3);
    }
  } else if (bid < 4640) {
    // ---- prep_wh: head weights -> Wh [64,512] bf16 (rows 54..63 zero) ----
    int e = (bid - 4608) * 1024 + t * 4;
    int m = e >> 9, c = e & 511;
    float v0 = 0.f, v1 = 0.f, v2 = 0.f, v3 = 0.f;
    if (m < 18) {
      const float* s = Wcls + m * 512 + c;
      v0 = s[0]; v1 = s[1]; v2 = s[2]; v3 = s[3];
    } else if (m < 54) {
      const float* s = Wbb + (m - 18) * 512 + c;
      v0 = s[0]; v1 = s[1]; v2 = s[2]; v3 = s[3];
    }
    ushort4_t pk; pk.x = f2bf(v0); pk.y = f2bf(v1); pk.z = f2bf(v2); pk.w = f2bf(v3);
    *(ushort4_t*)&Wh[e] = pk;
    if (bid == 4608 && t < 4) accbuf[t] = 0.f;
  } else {
    // ---- borders: zero-pad halo of xt ----
    int bid2 = bid - 4640;
    int b = bid2 / 66, h = bid2 % 66;
    unsigned char* base = xt + (long)(b * 66 + h) * 50 * 1024;
    int4v z = {};
    if (h == 0 || h == 65) {
      for (int i = t; i < 3200; i += 256) *(int4v*)(base + (long)i * 16) = z;
    } else if (t < 128) {
      int which = t >> 6, off = t & 63;
      *(int4v*)(base + (long)which * 49 * 1024 + (long)off * 16) = z;
    }
  }
}

// ---------------- main conv GEMM (MX-fp8): M=512, N=24576, K=9216 ------------------------
// v5: m201-style multi-phase schedule. BM=256, BN=192, BK=128. grid (128,2) = 256 blocks
// = exactly 1 block/CU. 512 threads = 8 waves (4M x 2N), wave tile 64x96 (24 MFMA/step).
// LDS 112 KB: A dbuf 2x32 KB + B dbuf 2x24 KB. Per K-step:
//   top: issue B(k+1) [3/thread]; s_waitcnt vmcnt(3) (drains stage(k)=7, leaves B(k+1));
//        s_barrier  -> stage(k) visible to all waves. NEVER vmcnt(0) in steady state.
//   P0: ds_read af[0..3]+bfr[0,1] (12xb128); issue A(k+1) s0,s1; bar; lgkm0; 8 MFMA; bar
//   P1: ds_read bfr[2,3] (4); issue A(k+1) s2,s3; bar; lgkm0; 8 MFMA; bar
//   P2: ds_read bfr[4,5] (4); bar; lgkm0; 8 MFMA; bar
// Restage safety: buffer nxt's last reads completed at step k-1's per-phase lgkm0 +
// closing barrier (crossed before any k-top issue). Read-once fragments (20 b128/wave).
// 16B-chunk xor swizzle unchanged: phys_chunk = q ^ (r&7), pre-swizzled global source.
__global__ __launch_bounds__(512, 2)
void conv_gemm(const unsigned char* __restrict__ Wa, const unsigned char* __restrict__ xt,
               const float* __restrict__ bias, unsigned short* __restrict__ conv1) {
  __shared__ unsigned char As_[2][256 * 128];     // 2 x 32 KB
  __shared__ unsigned char Bs_[2][192 * 128];     // 2 x 24 KB
  int t = threadIdx.x;               // 0..511
  int lane = t & 63, wv = t >> 6;    // 8 waves
  int m0 = blockIdx.y * 256;
  int n0 = blockIdx.x * 192;
  int wm = wv >> 1, wn = wv & 1;     // 4(M) x 2(N)
  int quad = lane >> 4, col = lane & 15;

  // staging sources: pre-swizzled global addresses, linear LDS dests (rule #21)
  const unsigned char* aSrc[4];
  for (int s = 0; s < 4; ++s) {
    int c = s * 512 + t;             // chunk 0..2047
    int r = c >> 3;                  // row 0..255
    int q = (c & 7) ^ (r & 7);
    aSrc[s] = Wa + (long)(m0 + r) * K9 + q * 16;
  }
  const unsigned char* bSrc[3];
  for (int p = 0; p < 3; ++p) {
    int c = p * 512 + t;             // chunk 0..1535
    int r = c >> 3;                  // row 0..191
    int q = (c & 7) ^ (r & 7);
    int n = n0 + r; int b = n / HW; int rem = n % HW; int h = rem / W_; int w = rem % W_;
    bSrc[p] = xt + ((long)(b * HP + h) * WP + w) * CIN + q * 16;
  }

  float4_t acc[4][6] = {};

  auto stageB = [&](int buf, int kt) {           // 3 loads/thread
    int off = kt >> 3;                           // which of the 9 (dy,dx) taps
    int dy = off / 3, dx = off % 3;
    long boff = (long)(dy * WP + dx) * CIN + (kt & 7) * 128;
    for (int p = 0; p < 3; ++p)
      async16(bSrc[p] + boff, &Bs_[buf][p * 8192 + t * 16]);
  };
  auto stageA2 = [&](int buf, int kt, int s0) {  // 2 loads/thread
    long aoff = (long)kt * 128;
    for (int s = s0; s < s0 + 2; ++s)
      async16(aSrc[s] + aoff, &As_[buf][s * 8192 + t * 16]);
  };

  // prologue: full stage of K-step 0 into buf0, queue order [B x3, A x4]
  stageB(0, 0);
  stageA2(0, 0, 0);
  stageA2(0, 0, 2);

#pragma unroll 1
  for (int kt = 0; kt < 72; ++kt) {
    int cur = kt & 1, nxt = cur ^ 1;
    // ---- step top: issue B(kt+1); acquire stage(kt) ----
    if (kt < 71) {
      stageB(nxt, kt + 1);
      // outstanding: [B(kt)3, A(kt)4, B(kt+1)3]; drain oldest 7 = stage(kt)
      asm volatile("s_waitcnt vmcnt(3)\n\ts_barrier" ::: "memory");
    } else {
      asm volatile("s_waitcnt vmcnt(0)\n\ts_barrier" ::: "memory");
    }
    const unsigned char* A  = As_[cur];
    const unsigned char* Bc = Bs_[cur];
    int8v af[4], bfr[6];
    // ================= phase 0: af[0..3] + bfr[0,1]; stage A(k+1) s0,s1; 8 MFMA ========
    for (int i = 0; i < 4; ++i) {
      int r = wm * 64 + i * 16 + col;
      int rb = r * 128, x7 = r & 7;
      int4v lo = *(const int4v*)&A[rb + (((quad * 2 + 0) ^ x7) << 4)];
      int4v hi = *(const int4v*)&A[rb + (((quad * 2 + 1) ^ x7) << 4)];
      af[i] = (int8v){lo.x, lo.y, lo.z, lo.w, hi.x, hi.y, hi.z, hi.w};
    }
    for (int j = 0; j < 2; ++j) {
      int r = wn * 96 + j * 16 + col;
      int rb = r * 128, x7 = r & 7;
      int4v lo = *(const int4v*)&Bc[rb + (((quad * 2 + 0) ^ x7) << 4)];
      int4v hi = *(const int4v*)&Bc[rb + (((quad * 2 + 1) ^ x7) << 4)];
      bfr[j] = (int8v){lo.x, lo.y, lo.z, lo.w, hi.x, hi.y, hi.z, hi.w};
    }
    if (kt < 71) stageA2(nxt, kt + 1, 0);
    asm volatile("s_barrier" ::: "memory");
    asm volatile("s_waitcnt lgkmcnt(0)" ::: "memory");
    __builtin_amdgcn_sched_barrier(0);
    __builtin_amdgcn_s_setprio(1);
    for (int i = 0; i < 4; ++i)
      for (int j = 0; j < 2; ++j)
        // A=W scaled by 2^9 -> e8m0 118 (2^-9); B=x scaled by 2^4 -> e8m0 123 (2^-4)
        acc[i][j] = __builtin_amdgcn_mfma_scale_f32_16x16x128_f8f6f4(
            af[i], bfr[j], acc[i][j], 0, 0, 0, 0x76767676, 0, 0x7B7B7B7B);
    __builtin_amdgcn_s_setprio(0);
    asm volatile("s_barrier" ::: "memory");
    // ================= phase 1: bfr[2,3]; stage A(k+1) s2,s3; 8 MFMA ===================
    for (int j = 2; j < 4; ++j) {
      int r = wn * 96 + j * 16 + col;
      int rb = r * 128, x7 = r & 7;
      int4v lo = *(const int4v*)&Bc[rb + (((quad * 2 + 0) ^ x7) << 4)];
      int4v hi = *(const int4v*)&Bc[rb + (((quad * 2 + 1) ^ x7) << 4)];
      bfr[j] = (int8v){lo.x, lo.y, lo.z, lo.w, hi.x, hi.y, hi.z, hi.w};
    }
    if (kt < 71) stageA2(nxt, kt + 1, 2);
    asm volatile("s_barrier" ::: "memory");
    asm volatile("s_waitcnt lgkmcnt(0)" ::: "memory");
    __builtin_amdgcn_sched_barrier(0);
    __builtin_amdgcn_s_setprio(1);
    for (int i = 0; i < 4; ++i)
      for (int j = 2; j < 4; ++j)
        acc[i][j] = __builtin_amdgcn_mfma_scale_f32_16x16x128_f8f6f4(
            af[i], bfr[j], acc[i][j], 0, 0, 0, 0x76767676, 0, 0x7B7B7B7B);
    __builtin_amdgcn_s_setprio(0);
    asm volatile("s_barrier" ::: "memory");
    // ================= phase 2: bfr[4,5]; 8 MFMA =======================================
    for (int j = 4; j < 6; ++j) {
      int r = wn * 96 + j * 16 + col;
      int rb = r * 128, x7 = r & 7;
      int4v lo = *(const int4v*)&Bc[rb + (((quad * 2 + 0) ^ x7) << 4)];
      int4v hi = *(const int4v*)&Bc[rb + (((quad * 2 + 1) ^ x7) << 4)];
      bfr[j] = (int8v){lo.x, lo.y, lo.z, lo.w, hi.x, hi.y, hi.z, hi.w};
    }
    asm volatile("s_barrier" ::: "memory");
    asm volatile("s_waitcnt lgkmcnt(0)" ::: "memory");
    __builtin_amdgcn_sched_barrier(0);
    __builtin_amdgcn_s_setprio(1);
    for (int i = 0; i < 4; ++i)
      for (int j = 4; j < 6; ++j)
        acc[i][j] = __builtin_amdgcn_mfma_scale_f32_16x16x128_f8f6f4(
            af[i], bfr[j], acc[i][j], 0, 0, 0, 0x76767676, 0, 0x7B7B7B7B);
    __builtin_amdgcn_s_setprio(0);
    asm volatile("s_barrier" ::: "memory");
  }

  // epilogue: bias + relu, store bf16 conv1[n*512 + m], 8B packed along m
  for (int i = 0; i < 4; ++i) {
    int mb = m0 + wm * 64 + i * 16 + quad * 4;
    float b0 = bias[mb + 0], b1 = bias[mb + 1], b2 = bias[mb + 2], b3 = bias[mb + 3];
    for (int j = 0; j < 6; ++j) {
      int n = n0 + wn * 96 + j * 16 + col;
      ushort4_t pk;
      pk.x = f2bf(fmaxf(acc[i][j].x + b0, 0.f));
      pk.y = f2bf(fmaxf(acc[i][j].y + b1, 0.f));
      pk.z = f2bf(fmaxf(acc[i][j].z + b2, 0.f));
      pk.w = f2bf(fmaxf(acc[i][j].w + b3, 0.f));
      *(ushort4_t*)&conv1[(long)n * 512 + mb] = pk;
    }
  }
}

// ---------------- head GEMM: [64 x 512] @ conv1^T -> cls_score (ws) + bbox_pred (d_out) --
// M=64 (54 used), N=24576, K=512. Tile 64(N) x BK=128. grid 384, 256 threads.
// 16B-chunk xor swizzle (16 chunks/row): phys = q ^ (r&15)
__global__ __launch_bounds__(256, 2)
void head_gemm(const unsigned short* __restrict__ Wh, const unsigned short* __restrict__ conv1,
               const float* __restrict__ b_cls, const float* __restrict__ b_bbox,
               float* __restrict__ cls_ws, float* __restrict__ out_bbox) {
  __shared__ unsigned short As[64 * 128];   // 16 KB
  __shared__ unsigned short Bs[64 * 128];   // 16 KB
  int t = threadIdx.x;
  int lane = t & 63, wv = t >> 6;
  int n0 = blockIdx.x * 64;
  int quad = lane >> 4, col = lane & 15;
  const unsigned short* aS[4];
  const unsigned short* bS[4];
  for (int p = 0; p < 4; ++p) {
    int c = p * 256 + t;
    int r = c >> 4;
    int q = (c & 15) ^ (r & 15);
    aS[p] = Wh + (long)r * 512 + q * 8;
    bS[p] = conv1 + (long)(n0 + r) * 512 + q * 8;
  }
  float4_t acc[4] = {};
  for (int kt = 0; kt < 4; ++kt) {
    long koff = (long)kt * 128;
    __syncthreads();
    for (int p = 0; p < 4; ++p) async16(aS[p] + koff, &As[p * 2048 + wv * 512]);
    for (int p = 0; p < 4; ++p) async16(bS[p] + koff, &Bs[p * 2048 + wv * 512]);
    __syncthreads();
    for (int ks = 0; ks < 4; ++ks) {
      int rn = wv * 16 + col;
      bf16x8 bfr = *(const bf16x8*)&Bs[rn * 128 + (((ks * 4 + quad) ^ (rn & 15)) << 3)];
      for (int i = 0; i < 4; ++i) {
        int r = i * 16 + col;
        bf16x8 af = *(const bf16x8*)&As[r * 128 + (((ks * 4 + quad) ^ (r & 15)) << 3)];
        acc[i] = __builtin_amdgcn_mfma_f32_16x16x32_bf16(af, bfr, acc[i], 0, 0, 0);
      }
    }
  }
  int n = n0 + wv * 16 + col;
  int b = n / HW; int rem = n % HW;   // rem = h*48 + w
  for (int i = 0; i < 4; ++i) {
    for (int r = 0; r < 4; ++r) {
      int m = i * 16 + quad * 4 + r;
      float v = acc[i][r];
      if (m < 18) {
        cls_ws[(long)(b * 18 + m) * HW + rem] = v + b_cls[m];
      } else if (m < 54) {
        out_bbox[(long)(b * 36 + (m - 18)) * HW + rem] = v + b_bbox[m - 18];
      }
    }
  }
}

// ---------------- fused losses: softmax+NLL (blocks 0..863) | smooth-L1 box (864..2591) --
__global__ void loss_fused(const float* __restrict__ cls, const int* __restrict__ label,
                           float* __restrict__ prob,
                           const float* __restrict__ pred, const float* __restrict__ tgt,
                           const float* __restrict__ iw, const float* __restrict__ ow,
                           float* __restrict__ acc) {
  int lane = threadIdx.x & 63, wv = threadIdx.x >> 6;
  __shared__ float red[8];
  if (blockIdx.x < 864) {
    int idx = blockIdx.x * 256 + threadIdx.x;
    int b = idx / 27648; int r = idx % 27648;
    int a = r / HW; int r2 = r % HW;
    long i0 = (long)(b * 18 + a) * HW + r2;
    long i1 = i0 + (long)9 * HW;
    float x0 = cls[i0], x1 = cls[i1];
    float mx = fmaxf(x0, x1);
    float e0 = __expf(x0 - mx), e1 = __expf(x1 - mx);
    float s = e0 + e1;
    prob[i0] = e0 / s;
    prob[i1] = e1 / s;
    int lb = label[idx];
    float nll = 0.f, val = 0.f;
    if (lb != -1) {
      val = 1.f;
      float xl = (lb > 0) ? x1 : x0;
      nll = -(xl - mx - __logf(s));
    }
    nll = wave_sum(nll);
    val = wave_sum(val);
    if (lane == 0) { red[wv] = nll; red[4 + wv] = val; }
    __syncthreads();
    if (threadIdx.x == 0) {
      atomicAdd(&acc[0], red[0] + red[1] + red[2] + red[3]);
      atomicAdd(&acc[1], red[4] + red[5] + red[6] + red[7]);
    }
  } else {
    int bid = blockIdx.x - 864;
    float s = 0.f;
    const long total = (long)B_ * 36 * HW;   // 884736
    for (long i = (long)bid * 256 + threadIdx.x; i < total; i += (long)1728 * 256) {
      float d = iw[i] * (pred[i] - tgt[i]);
      float ad = fabsf(d);
      float l = (ad < (1.f / 9.f)) ? d * d * 4.5f : ad - (1.f / 18.f);
      s += ow[i] * l;
    }
    s = wave_sum(s);
    if (lane == 0) red[wv] = s;
    __syncthreads();
    if (threadIdx.x == 0) atomicAdd(&acc[2], red[0] + red[1] + red[2] + red[3]);
  }
}

__global__ void finalize(const float* __restrict__ acc, float* __restrict__ out) {
  if (threadIdx.x == 0) {
    out[0] = acc[0] / fmaxf(acc[1], 1.f);
    out[1] = acc[2] / (float)B_;
  }
}

extern "C" void kernel_launch(void* const* d_in, const int* in_sizes, int n_in,
                              void* d_out, int out_size, void* d_ws, size_t ws_size,
                              hipStream_t stream) {
  const float* base_feat = (const float*)d_in[0];
  const float* W_conv    = (const float*)d_in[1];
  const float* b_conv    = (const float*)d_in[2];
  const float* W_cls     = (const float*)d_in[3];
  const float* b_cls     = (const float*)d_in[4];
  const float* W_bbox    = (const float*)d_in[5];
  const float* b_bbox    = (const float*)d_in[6];
  const int*   rpn_label = (const int*)d_in[7];
  const float* bb_tgt    = (const float*)d_in[8];
  const float* bb_iw     = (const float*)d_in[9];
  const float* bb_ow     = (const float*)d_in[10];

  float* out = (float*)d_out;
  float* out_cls_prob = out;                         // 442368
  float* out_bbox     = out + 442368;                // 884736
  float* out_scalars  = out + 442368 + 884736;       // 2

  // workspace layout
  size_t off = 0;
  auto alloc = [&](size_t bytes) {
    void* p = (char*)d_ws + off;
    off = (off + bytes + 255) & ~(size_t)255;
    return p;
  };
  const size_t XT_BYTES = (size_t)B_ * HP * WP * CIN;              // 27,033,600 (fp8)
  unsigned char*  xt    = (unsigned char*)alloc(XT_BYTES);
  unsigned char*  Wa    = (unsigned char*)alloc((size_t)OC * K9);
  unsigned short* conv1 = (unsigned short*)alloc((size_t)NPOS * OC * 2);
  unsigned short* Wh    = (unsigned short*)alloc((size_t)64 * 512 * 2);
  float* cls_ws         = (float*)alloc((size_t)B_ * 18 * HW * 4);
  float* accbuf         = (float*)alloc(16);

  prep_fused<<<5168, 256, 0, stream>>>(base_feat, W_conv, W_cls, W_bbox, xt, Wa, Wh, accbuf);
  conv_gemm<<<dim3(128, 2), 512, 0, stream>>>(Wa, xt, b_conv, conv1);
  head_gemm<<<384, 256, 0, stream>>>(Wh, conv1, b_cls, b_bbox, cls_ws, out_bbox);
  loss_fused<<<2592, 256, 0, stream>>>(cls_ws, rpn_label, out_cls_prob,
                                       out_bbox, bb_tgt, bb_iw, bb_ow, accbuf);
  finalize<<<1, 64, 0, stream>>>(accbuf, out_scalars);
}

// Round 6
// 333.232 us; speedup vs baseline: 1.2246x; 1.1111x over previous
//
#include <hip/hip_runtime.h>
#include <stdint.h>

// Problem constants
#define B_    8
#define CIN   1024
#define H_    64
#define W_    48
#define OC    512
#define HW    3072          // H*W
#define NPOS  24576         // B*H*W
#define K9    9216          // 9*CIN
#define HP    66            // H+2
#define WP    50            // W+2

typedef __attribute__((ext_vector_type(8))) __bf16 bf16x8;
typedef __attribute__((ext_vector_type(4))) float  float4_t;
typedef __attribute__((ext_vector_type(4))) unsigned short ushort4_t;
typedef __attribute__((ext_vector_type(8))) int int8v;
typedef __attribute__((ext_vector_type(4))) int int4v;

__device__ __forceinline__ unsigned short f2bf(float x) {
  union { float f; unsigned u; } v; v.f = x;
  unsigned r = v.u + 0x7FFFu + ((v.u >> 16) & 1u);
  return (unsigned short)(r >> 16);
}

// pack 4 floats -> 4 fp8 e4m3 bytes (RNE, saturating)
__device__ __forceinline__ unsigned int pack4_fp8(float a, float b, float c, float d) {
  int w = __builtin_amdgcn_cvt_pk_fp8_f32(a, b, 0, false);   // bytes 0,1
  w = __builtin_amdgcn_cvt_pk_fp8_f32(c, d, w, true);        // bytes 2,3
  return (unsigned int)w;
}

__device__ __forceinline__ void async16(const void* g, void* l) {
  __builtin_amdgcn_global_load_lds(
      (const __attribute__((address_space(1))) unsigned int*)g,
      (__attribute__((address_space(3))) unsigned int*)l, 16, 0, 0);
}

__device__ __forceinline__ float wave_sum(float v) {
  for (int o = 32; o > 0; o >>= 1) v += __shfl_down(v, o, 64);
  return v;
}

// ================= fused prep: prep_x | prep_w | prep_wh | borders ======================
// grid = 4096 (prep_x) + 512 (prep_w) + 32 (prep_wh) + 528 (borders) = 5168, 256 threads
__global__ void prep_fused(const float* __restrict__ x, const float* __restrict__ Wc,
                           const float* __restrict__ Wcls, const float* __restrict__ Wbb,
                           unsigned char* __restrict__ xt, unsigned char* __restrict__ Wa,
                           unsigned short* __restrict__ Wh, float* __restrict__ accbuf) {
  __shared__ float smem[9216];   // 36 KB shared across branches
  int bid = blockIdx.x, t = threadIdx.x;
  if (bid < 4096) {
    // ---- prep_x: pad+transpose NCHW fp32 -> NHWC fp8 (x16), one (b,h,128c) slice ----
    int cx = bid & 7, h = (bid >> 3) & 63, b = bid >> 9;
    float* tile = smem;   // [128][49]
    const float* src = x + ((long)(b * CIN + cx * 128) * H_ + h) * W_;
    for (int it = 0; it < 6; ++it) {
      int e = it * 256 + t;
      int cl = e / 12, w4 = e % 12;
      float4_t v = *(const float4_t*)&src[(long)cl * HW + w4 * 4];
      int base = cl * 49 + w4 * 4;
      tile[base] = v.x; tile[base + 1] = v.y; tile[base + 2] = v.z; tile[base + 3] = v.w;
    }
    __syncthreads();
    unsigned char* dst = xt + ((long)(b * HP + h + 1) * WP + 1) * CIN + cx * 128;
    for (int it = 0; it < 6; ++it) {
      int e = it * 256 + t;
      int w = e >> 5, g = e & 31;
      float v0 = tile[(g * 4 + 0) * 49 + w] * 16.f;
      float v1 = tile[(g * 4 + 1) * 49 + w] * 16.f;
      float v2 = tile[(g * 4 + 2) * 49 + w] * 16.f;
      float v3 = tile[(g * 4 + 3) * 49 + w] * 16.f;
      *(unsigned int*)&dst[(long)w * CIN + g * 4] = pack4_fp8(v0, v1, v2, v3);
    }
  } else if (bid < 4608) {
    // ---- prep_w: W_conv [512,1024,3,3] -> Wa [512,9216] fp8 (x512), k=(off*1024+c) ----
    int o = bid - 4096;
    float* lw = smem;   // [9216]
    const float* src = Wc + (long)o * K9;
    for (int i = 0; i < 9; ++i)
      *(float4_t*)&lw[i * 1024 + t * 4] = *(const float4_t*)&src[i * 1024 + t * 4];
    __syncthreads();
    unsigned char* dst = Wa + (long)o * K9;
    int c = t * 4;
    for (int off = 0; off < 9; ++off) {
      float v0 = lw[(c + 0) * 9 + off] * 512.f;
      float v1 = lw[(c + 1) * 9 + off] * 512.f;
      float v2 = lw[(c + 2) * 9 + off] * 512.f;
      float v3 = lw[(c + 3) * 9 + off] * 512.f;
      *(unsigned int*)&dst[off * 1024 + c] = pack4_fp8(v0, v1, v2, v3);
    }
  } else if (bid < 4640) {
    // ---- prep_wh: head weights -> Wh [64,512] bf16 (rows 54..63 zero) ----
    int e = (bid - 4608) * 1024 + t * 4;
    int m = e >> 9, c = e & 511;
    float v0 = 0.f, v1 = 0.f, v2 = 0.f, v3 = 0.f;
    if (m < 18) {
      const float* s = Wcls + m * 512 + c;
      v0 = s[0]; v1 = s[1]; v2 = s[2]; v3 = s[3];
    } else if (m < 54) {
      const float* s = Wbb + (m - 18) * 512 + c;
      v0 = s[0]; v1 = s[1]; v2 = s[2]; v3 = s[3];
    }
    ushort4_t pk; pk.x = f2bf(v0); pk.y = f2bf(v1); pk.z = f2bf(v2); pk.w = f2bf(v3);
    *(ushort4_t*)&Wh[e] = pk;
    if (bid == 4608 && t < 4) accbuf[t] = 0.f;
  } else {
    // ---- borders: zero-pad halo of xt ----
    int bid2 = bid - 4640;
    int b = bid2 / 66, h = bid2 % 66;
    unsigned char* base = xt + (long)(b * 66 + h) * 50 * 1024;
    int4v z = {};
    if (h == 0 || h == 65) {
      for (int i = t; i < 3200; i += 256) *(int4v*)(base + (long)i * 16) = z;
    } else if (t < 128) {
      int which = t >> 6, off = t & 63;
      *(int4v*)(base + (long)which * 49 * 1024 + (long)off * 16) = z;
    }
  }
}

// ---------------- main conv GEMM (MX-fp8): M=512, N=24576, K=9216 ------------------------
// v6: v3 geometry (128x192, 4 waves, grid (128,4)=512=2/CU) + CHUNK-OUTER B staging.
// K-loop = cc (8 c-chunks of 128) outer x tap (9) inner. B tile [6 rows][50 w][128c] =
// 37.5 KB staged ONCE per chunk, persists across all 9 taps (taps = LDS address offsets
// (dy*50+dx)*128). Cuts B LDS-write traffic 9x (1.73 MB -> 300 KB per block) and B L2
// re-fetch 5.8x. A: dbuf 2x16 KB, staged per tap (post-release, flies under MFMA).
// Acquire = vmcnt(0)+bar (drains only loads issued one MFMA-phase earlier). 2 bar/tap.
// LDS 72 KB -> 2 blocks/CU. Swizzle: 16B-chunk xor, phys = q ^ (pos&7), pre-swizzled src.
__global__ __launch_bounds__(256, 2)
void conv_gemm(const unsigned char* __restrict__ Wa, const unsigned char* __restrict__ xt,
               const float* __restrict__ bias, unsigned short* __restrict__ conv1) {
  __shared__ unsigned char As_[2][128 * 128];   // 2 x 16 KB
  __shared__ unsigned char Bt[2560 * 16];       // 40 KB ([320 pos][128 B], 300 used)
  int t = threadIdx.x;
  int lane = t & 63, wv = t >> 6;
  int m0 = blockIdx.y * 128;
  int n0 = blockIdx.x * 192;
  int wm = wv >> 1, wn = wv & 1;
  int quad = lane >> 4, col = lane & 15;
  int bB = n0 / HW;                   // batch of this N-tile
  int h0 = (n0 % HW) / W_;            // first output row (multiple of 4); w0 = 0

  // ---- B staging sources (chunk-outer): 10 loads/thread, position-clamped slack ----
  // linear chunk c = i*256 + t -> pos p = c>>3, phys slot s = c&7 holds logical q = s^(p&7)
  long bOff[10];
  for (int i = 0; i < 10; ++i) {
    int c = i * 256 + t;
    int p = c >> 3, s = c & 7;
    int pc = (p < 300) ? p : 0;       // clamp slack positions (data unused)
    int q = s ^ (pc & 7);
    int r = pc / 50, w = pc % 50;     // staged padded rows h0..h0+5, w 0..49
    bOff[i] = ((long)(bB * HP + h0 + r) * WP + w) * CIN + q * 16;
  }
  auto stageB = [&](int cc) {
    long co = (long)cc * 128;
    for (int i = 0; i < 10; ++i)
      async16(xt + bOff[i] + co, &Bt[(i * 256 + wv * 64) * 16]);
  };

  // ---- A staging sources (v3 scheme): pre-swizzled rows, 4 loads/thread ----
  const unsigned char* aSrc[4];
  for (int s = 0; s < 4; ++s) {
    int c = s * 256 + t;
    int r = c >> 3;
    int q = (c & 7) ^ (r & 7);
    aSrc[s] = Wa + (long)(m0 + r) * K9 + q * 16;
  }
  auto stageA = [&](int buf, int aoff) {
    for (int s = 0; s < 4; ++s)
      async16(aSrc[s] + aoff, &As_[buf][s * 4096 + wv * 1024]);
  };

  // ---- per-lane B read position bases: pbase[j] for output n = wn*96 + j*16 + col ----
  int pbase[6];
  for (int j = 0; j < 6; ++j) {
    int nl = wn * 96 + j * 16 + col;
    int hl = nl / W_, wl = nl % W_;
    pbase[j] = hl * 50 + wl;          // tap (dy,dx) reads pos pbase + dy*50 + dx
  }

  float4_t acc[4][6] = {};
  int q2 = quad * 2;

  // prologue: B chunk 0 + A (cc=0,tap=0) -> buf 0
  stageB(0);
  stageA(0, 0);
  int abuf = 0;

#pragma unroll 1
  for (int cc = 0; cc < 8; ++cc) {
#pragma unroll 1
    for (int tap = 0; tap < 9; ++tap) {
      // ---- acquire: stage(cur) landed, visible to all waves ----
      asm volatile("s_waitcnt vmcnt(0)\n\ts_barrier" ::: "memory");
      const unsigned char* A = As_[abuf];
      int dy = tap / 3, dx = tap - dy * 3;
      int doff = dy * 50 + dx;        // uniform
      int8v af[4], bfr[6];
      for (int i = 0; i < 4; ++i) {
        int r = wm * 64 + i * 16 + col;
        int rb = r * 128, x7 = r & 7;
        int4v lo = *(const int4v*)&A[rb + (((q2 + 0) ^ x7) << 4)];
        int4v hi = *(const int4v*)&A[rb + (((q2 + 1) ^ x7) << 4)];
        af[i] = (int8v){lo.x, lo.y, lo.z, lo.w, hi.x, hi.y, hi.z, hi.w};
      }
      for (int j = 0; j < 6; ++j) {
        int pj = pbase[j] + doff;
        int rb = pj << 7, x7 = pj & 7;
        int4v lo = *(const int4v*)&Bt[rb + (((q2 + 0) ^ x7) << 4)];
        int4v hi = *(const int4v*)&Bt[rb + (((q2 + 1) ^ x7) << 4)];
        bfr[j] = (int8v){lo.x, lo.y, lo.z, lo.w, hi.x, hi.y, hi.z, hi.w};
      }
      // ---- release: all waves' reads of A(abuf) (and, at tap 8, of Bt) complete ----
      asm volatile("s_waitcnt lgkmcnt(0)\n\ts_barrier" ::: "memory");
      __builtin_amdgcn_sched_barrier(0);
      // ---- prefetch next (flies under the MFMA cluster) ----
      int nt = tap + 1, ncc = cc;
      if (nt == 9) { nt = 0; ++ncc; }
      if (ncc < 8) {
        stageA(abuf ^ 1, nt * 1024 + ncc * 128);
        if (nt == 0) stageB(ncc);
      }
      __builtin_amdgcn_sched_barrier(0);
      __builtin_amdgcn_s_setprio(1);
      for (int i = 0; i < 4; ++i)
        for (int j = 0; j < 6; ++j)
          // A=W scaled by 2^9 -> e8m0 118 (2^-9); B=x scaled by 2^4 -> e8m0 123 (2^-4)
          acc[i][j] = __builtin_amdgcn_mfma_scale_f32_16x16x128_f8f6f4(
              af[i], bfr[j], acc[i][j], 0, 0, 0, 0x76767676, 0, 0x7B7B7B7B);
      __builtin_amdgcn_s_setprio(0);
      __builtin_amdgcn_sched_barrier(0);
      abuf ^= 1;
    }
  }

  // epilogue: bias + relu, store bf16 conv1[n*512 + m], 8B packed along m
  for (int i = 0; i < 4; ++i) {
    int mb = m0 + wm * 64 + i * 16 + quad * 4;
    float b0 = bias[mb + 0], b1 = bias[mb + 1], b2 = bias[mb + 2], b3 = bias[mb + 3];
    for (int j = 0; j < 6; ++j) {
      int n = n0 + wn * 96 + j * 16 + col;
      ushort4_t pk;
      pk.x = f2bf(fmaxf(acc[i][j].x + b0, 0.f));
      pk.y = f2bf(fmaxf(acc[i][j].y + b1, 0.f));
      pk.z = f2bf(fmaxf(acc[i][j].z + b2, 0.f));
      pk.w = f2bf(fmaxf(acc[i][j].w + b3, 0.f));
      *(ushort4_t*)&conv1[(long)n * 512 + mb] = pk;
    }
  }
}

// ---------------- head GEMM: [64 x 512] @ conv1^T -> cls_score (ws) + bbox_pred (d_out) --
// M=64 (54 used), N=24576, K=512. Tile 64(N) x BK=128. grid 384, 256 threads.
// 16B-chunk xor swizzle (16 chunks/row): phys = q ^ (r&15)
__global__ __launch_bounds__(256, 2)
void head_gemm(const unsigned short* __restrict__ Wh, const unsigned short* __restrict__ conv1,
               const float* __restrict__ b_cls, const float* __restrict__ b_bbox,
               float* __restrict__ cls_ws, float* __restrict__ out_bbox) {
  __shared__ unsigned short As[64 * 128];   // 16 KB
  __shared__ unsigned short Bs[64 * 128];   // 16 KB
  int t = threadIdx.x;
  int lane = t & 63, wv = t >> 6;
  int n0 = blockIdx.x * 64;
  int quad = lane >> 4, col = lane & 15;
  const unsigned short* aS[4];
  const unsigned short* bS[4];
  for (int p = 0; p < 4; ++p) {
    int c = p * 256 + t;
    int r = c >> 4;
    int q = (c & 15) ^ (r & 15);
    aS[p] = Wh + (long)r * 512 + q * 8;
    bS[p] = conv1 + (long)(n0 + r) * 512 + q * 8;
  }
  float4_t acc[4] = {};
  for (int kt = 0; kt < 4; ++kt) {
    long koff = (long)kt * 128;
    __syncthreads();
    for (int p = 0; p < 4; ++p) async16(aS[p] + koff, &As[p * 2048 + wv * 512]);
    for (int p = 0; p < 4; ++p) async16(bS[p] + koff, &Bs[p * 2048 + wv * 512]);
    __syncthreads();
    for (int ks = 0; ks < 4; ++ks) {
      int rn = wv * 16 + col;
      bf16x8 bfr = *(const bf16x8*)&Bs[rn * 128 + (((ks * 4 + quad) ^ (rn & 15)) << 3)];
      for (int i = 0; i < 4; ++i) {
        int r = i * 16 + col;
        bf16x8 af = *(const bf16x8*)&As[r * 128 + (((ks * 4 + quad) ^ (r & 15)) << 3)];
        acc[i] = __builtin_amdgcn_mfma_f32_16x16x32_bf16(af, bfr, acc[i], 0, 0, 0);
      }
    }
  }
  int n = n0 + wv * 16 + col;
  int b = n / HW; int rem = n % HW;   // rem = h*48 + w
  for (int i = 0; i < 4; ++i) {
    for (int r = 0; r < 4; ++r) {
      int m = i * 16 + quad * 4 + r;
      float v = acc[i][r];
      if (m < 18) {
        cls_ws[(long)(b * 18 + m) * HW + rem] = v + b_cls[m];
      } else if (m < 54) {
        out_bbox[(long)(b * 36 + (m - 18)) * HW + rem] = v + b_bbox[m - 18];
      }
    }
  }
}

// ---------------- fused losses: softmax+NLL (blocks 0..863) | smooth-L1 box (864..2591) --
__global__ void loss_fused(const float* __restrict__ cls, const int* __restrict__ label,
                           float* __restrict__ prob,
                           const float* __restrict__ pred, const float* __restrict__ tgt,
                           const float* __restrict__ iw, const float* __restrict__ ow,
                           float* __restrict__ acc) {
  int lane = threadIdx.x & 63, wv = threadIdx.x >> 6;
  __shared__ float red[8];
  if (blockIdx.x < 864) {
    int idx = blockIdx.x * 256 + threadIdx.x;
    int b = idx / 27648; int r = idx % 27648;
    int a = r / HW; int r2 = r % HW;
    long i0 = (long)(b * 18 + a) * HW + r2;
    long i1 = i0 + (long)9 * HW;
    float x0 = cls[i0], x1 = cls[i1];
    float mx = fmaxf(x0, x1);
    float e0 = __expf(x0 - mx), e1 = __expf(x1 - mx);
    float s = e0 + e1;
    prob[i0] = e0 / s;
    prob[i1] = e1 / s;
    int lb = label[idx];
    float nll = 0.f, val = 0.f;
    if (lb != -1) {
      val = 1.f;
      float xl = (lb > 0) ? x1 : x0;
      nll = -(xl - mx - __logf(s));
    }
    nll = wave_sum(nll);
    val = wave_sum(val);
    if (lane == 0) { red[wv] = nll; red[4 + wv] = val; }
    __syncthreads();
    if (threadIdx.x == 0) {
      atomicAdd(&acc[0], red[0] + red[1] + red[2] + red[3]);
      atomicAdd(&acc[1], red[4] + red[5] + red[6] + red[7]);
    }
  } else {
    int bid = blockIdx.x - 864;
    float s = 0.f;
    const long total = (long)B_ * 36 * HW;   // 884736
    for (long i = (long)bid * 256 + threadIdx.x; i < total; i += (long)1728 * 256) {
      float d = iw[i] * (pred[i] - tgt[i]);
      float ad = fabsf(d);
      float l = (ad < (1.f / 9.f)) ? d * d * 4.5f : ad - (1.f / 18.f);
      s += ow[i] * l;
    }
    s = wave_sum(s);
    if (lane == 0) red[wv] = s;
    __syncthreads();
    if (threadIdx.x == 0) atomicAdd(&acc[2], red[0] + red[1] + red[2] + red[3]);
  }
}

__global__ void finalize(const float* __restrict__ acc, float* __restrict__ out) {
  if (threadIdx.x == 0) {
    out[0] = acc[0] / fmaxf(acc[1], 1.f);
    out[1] = acc[2] / (float)B_;
  }
}

extern "C" void kernel_launch(void* const* d_in, const int* in_sizes, int n_in,
                              void* d_out, int out_size, void* d_ws, size_t ws_size,
                              hipStream_t stream) {
  const float* base_feat = (const float*)d_in[0];
  const float* W_conv    = (const float*)d_in[1];
  const float* b_conv    = (const float*)d_in[2];
  const float* W_cls     = (const float*)d_in[3];
  const float* b_cls     = (const float*)d_in[4];
  const float* W_bbox    = (const float*)d_in[5];
  const float* b_bbox    = (const float*)d_in[6];
  const int*   rpn_label = (const int*)d_in[7];
  const float* bb_tgt    = (const float*)d_in[8];
  const float* bb_iw     = (const float*)d_in[9];
  const float* bb_ow     = (const float*)d_in[10];

  float* out = (float*)d_out;
  float* out_cls_prob = out;                         // 442368
  float* out_bbox     = out + 442368;                // 884736
  float* out_scalars  = out + 442368 + 884736;       // 2

  // workspace layout
  size_t off = 0;
  auto alloc = [&](size_t bytes) {
    void* p = (char*)d_ws + off;
    off = (off + bytes + 255) & ~(size_t)255;
    return p;
  };
  const size_t XT_BYTES = (size_t)B_ * HP * WP * CIN;              // 27,033,600 (fp8)
  unsigned char*  xt    = (unsigned char*)alloc(XT_BYTES);
  unsigned char*  Wa    = (unsigned char*)alloc((size_t)OC * K9);
  unsigned short* conv1 = (unsigned short*)alloc((size_t)NPOS * OC * 2);
  unsigned short* Wh    = (unsigned short*)alloc((size_t)64 * 512 * 2);
  float* cls_ws         = (float*)alloc((size_t)B_ * 18 * HW * 4);
  float* accbuf         = (float*)alloc(16);

  prep_fused<<<5168, 256, 0, stream>>>(base_feat, W_conv, W_cls, W_bbox, xt, Wa, Wh, accbuf);
  conv_gemm<<<dim3(128, 4), 256, 0, stream>>>(Wa, xt, b_conv, conv1);
  head_gemm<<<384, 256, 0, stream>>>(Wh, conv1, b_cls, b_bbox, cls_ws, out_bbox);
  loss_fused<<<2592, 256, 0, stream>>>(cls_ws, rpn_label, out_cls_prob,
                                       out_bbox, bb_tgt, bb_iw, bb_ow, accbuf);
  finalize<<<1, 64, 0, stream>>>(accbuf, out_scalars);
}

// Round 7
// 304.609 us; speedup vs baseline: 1.3397x; 1.0940x over previous
//
#include <hip/hip_runtime.h>
#include <stdint.h>

// Problem constants
#define B_    8
#define CIN   1024
#define H_    64
#define W_    48
#define OC    512
#define HW    3072          // H*W
#define NPOS  24576         // B*H*W
#define K9    9216          // 9*CIN
#define HP    66            // H+2
#define WP    50            // W+2

typedef __attribute__((ext_vector_type(8))) __bf16 bf16x8;
typedef __attribute__((ext_vector_type(4))) float  float4_t;
typedef __attribute__((ext_vector_type(4))) unsigned short ushort4_t;
typedef __attribute__((ext_vector_type(8))) int int8v;
typedef __attribute__((ext_vector_type(4))) int int4v;

__device__ __forceinline__ unsigned short f2bf(float x) {
  union { float f; unsigned u; } v; v.f = x;
  unsigned r = v.u + 0x7FFFu + ((v.u >> 16) & 1u);
  return (unsigned short)(r >> 16);
}

// pack 4 floats -> 4 fp8 e4m3 bytes (RNE, saturating)
__device__ __forceinline__ unsigned int pack4_fp8(float a, float b, float c, float d) {
  int w = __builtin_amdgcn_cvt_pk_fp8_f32(a, b, 0, false);   // bytes 0,1
  w = __builtin_amdgcn_cvt_pk_fp8_f32(c, d, w, true);        // bytes 2,3
  return (unsigned int)w;
}

__device__ __forceinline__ void async16(const void* g, void* l) {
  __builtin_amdgcn_global_load_lds(
      (const __attribute__((address_space(1))) unsigned int*)g,
      (__attribute__((address_space(3))) unsigned int*)l, 16, 0, 0);
}

__device__ __forceinline__ float wave_sum(float v) {
  for (int o = 32; o > 0; o >>= 1) v += __shfl_down(v, o, 64);
  return v;
}

// ================= fused prep: prep_x | prep_w | prep_wh | borders ======================
// grid = 4096 (prep_x) + 512 (prep_w) + 32 (prep_wh) + 528 (borders) = 5168, 256 threads
__global__ void prep_fused(const float* __restrict__ x, const float* __restrict__ Wc,
                           const float* __restrict__ Wcls, const float* __restrict__ Wbb,
                           unsigned char* __restrict__ xt, unsigned char* __restrict__ Wa,
                           unsigned short* __restrict__ Wh, float* __restrict__ accbuf) {
  __shared__ float smem[9216];   // 36 KB shared across branches
  int bid = blockIdx.x, t = threadIdx.x;
  if (bid < 4096) {
    // ---- prep_x: pad+transpose NCHW fp32 -> NHWC fp8 (x16), one (b,h,128c) slice ----
    int cx = bid & 7, h = (bid >> 3) & 63, b = bid >> 9;
    float* tile = smem;   // [128][49]
    const float* src = x + ((long)(b * CIN + cx * 128) * H_ + h) * W_;
    for (int it = 0; it < 6; ++it) {
      int e = it * 256 + t;
      int cl = e / 12, w4 = e % 12;
      float4_t v = *(const float4_t*)&src[(long)cl * HW + w4 * 4];
      int base = cl * 49 + w4 * 4;
      tile[base] = v.x; tile[base + 1] = v.y; tile[base + 2] = v.z; tile[base + 3] = v.w;
    }
    __syncthreads();
    unsigned char* dst = xt + ((long)(b * HP + h + 1) * WP + 1) * CIN + cx * 128;
    for (int it = 0; it < 6; ++it) {
      int e = it * 256 + t;
      int w = e >> 5, g = e & 31;
      float v0 = tile[(g * 4 + 0) * 49 + w] * 16.f;
      float v1 = tile[(g * 4 + 1) * 49 + w] * 16.f;
      float v2 = tile[(g * 4 + 2) * 49 + w] * 16.f;
      float v3 = tile[(g * 4 + 3) * 49 + w] * 16.f;
      *(unsigned int*)&dst[(long)w * CIN + g * 4] = pack4_fp8(v0, v1, v2, v3);
    }
  } else if (bid < 4608) {
    // ---- prep_w: W_conv [512,1024,3,3] -> Wa [512,9216] fp8 (x512), k=(off*1024+c) ----
    int o = bid - 4096;
    float* lw = smem;   // [9216]
    const float* src = Wc + (long)o * K9;
    for (int i = 0; i < 9; ++i)
      *(float4_t*)&lw[i * 1024 + t * 4] = *(const float4_t*)&src[i * 1024 + t * 4];
    __syncthreads();
    unsigned char* dst = Wa + (long)o * K9;
    int c = t * 4;
    for (int off = 0; off < 9; ++off) {
      float v0 = lw[(c + 0) * 9 + off] * 512.f;
      float v1 = lw[(c + 1) * 9 + off] * 512.f;
      float v2 = lw[(c + 2) * 9 + off] * 512.f;
      float v3 = lw[(c + 3) * 9 + off] * 512.f;
      *(unsigned int*)&dst[off * 1024 + c] = pack4_fp8(v0, v1, v2, v3);
    }
  } else if (bid < 4640) {
    // ---- prep_wh: head weights -> Wh [64,512] bf16 (rows 54..63 zero) ----
    int e = (bid - 4608) * 1024 + t * 4;
    int m = e >> 9, c = e & 511;
    float v0 = 0.f, v1 = 0.f, v2 = 0.f, v3 = 0.f;
    if (m < 18) {
      const float* s = Wcls + m * 512 + c;
      v0 = s[0]; v1 = s[1]; v2 = s[2]; v3 = s[3];
    } else if (m < 54) {
      const float* s = Wbb + (m - 18) * 512 + c;
      v0 = s[0]; v1 = s[1]; v2 = s[2]; v3 = s[3];
    }
    ushort4_t pk; pk.x = f2bf(v0); pk.y = f2bf(v1); pk.z = f2bf(v2); pk.w = f2bf(v3);
    *(ushort4_t*)&Wh[e] = pk;
    if (bid == 4608 && t < 4) accbuf[t] = 0.f;
  } else {
    // ---- borders: zero-pad halo of xt ----
    int bid2 = bid - 4640;
    int b = bid2 / 66, h = bid2 % 66;
    unsigned char* base = xt + (long)(b * 66 + h) * 50 * 1024;
    int4v z = {};
    if (h == 0 || h == 65) {
      for (int i = t; i < 3200; i += 256) *(int4v*)(base + (long)i * 16) = z;
    } else if (t < 128) {
      int which = t >> 6, off = t & 63;
      *(int4v*)(base + (long)which * 49 * 1024 + (long)off * 16) = z;
    }
  }
}

// ---------------- main conv GEMM (MX-fp8): M=512, N=24576, K=9216 ------------------------
// v6 (unchanged, proven 105 us / MfmaUtil 47%): v3 geometry (128x192, 4 waves, grid
// (128,4)=512=2/CU) + CHUNK-OUTER B staging. K-loop = cc (8 c-chunks of 128) outer x
// tap (9) inner. B tile [6 rows][50 w][128c] staged ONCE per chunk, persists across all
// 9 taps (taps = LDS address offsets (dy*50+dx)*128). A: dbuf 2x16 KB, staged per tap.
// LDS 72 KB -> 2 blocks/CU. Swizzle: 16B-chunk xor, phys = q ^ (pos&7), pre-swizzled src.
__global__ __launch_bounds__(256, 2)
void conv_gemm(const unsigned char* __restrict__ Wa, const unsigned char* __restrict__ xt,
               const float* __restrict__ bias, unsigned short* __restrict__ conv1) {
  __shared__ unsigned char As_[2][128 * 128];   // 2 x 16 KB
  __shared__ unsigned char Bt[2560 * 16];       // 40 KB ([320 pos][128 B], 300 used)
  int t = threadIdx.x;
  int lane = t & 63, wv = t >> 6;
  int m0 = blockIdx.y * 128;
  int n0 = blockIdx.x * 192;
  int wm = wv >> 1, wn = wv & 1;
  int quad = lane >> 4, col = lane & 15;
  int bB = n0 / HW;                   // batch of this N-tile
  int h0 = (n0 % HW) / W_;            // first output row (multiple of 4); w0 = 0

  // ---- B staging sources (chunk-outer): 10 loads/thread, position-clamped slack ----
  long bOff[10];
  for (int i = 0; i < 10; ++i) {
    int c = i * 256 + t;
    int p = c >> 3, s = c & 7;
    int pc = (p < 300) ? p : 0;       // clamp slack positions (data unused)
    int q = s ^ (pc & 7);
    int r = pc / 50, w = pc % 50;     // staged padded rows h0..h0+5, w 0..49
    bOff[i] = ((long)(bB * HP + h0 + r) * WP + w) * CIN + q * 16;
  }
  auto stageB = [&](int cc) {
    long co = (long)cc * 128;
    for (int i = 0; i < 10; ++i)
      async16(xt + bOff[i] + co, &Bt[(i * 256 + wv * 64) * 16]);
  };

  // ---- A staging sources (v3 scheme): pre-swizzled rows, 4 loads/thread ----
  const unsigned char* aSrc[4];
  for (int s = 0; s < 4; ++s) {
    int c = s * 256 + t;
    int r = c >> 3;
    int q = (c & 7) ^ (r & 7);
    aSrc[s] = Wa + (long)(m0 + r) * K9 + q * 16;
  }
  auto stageA = [&](int buf, int aoff) {
    for (int s = 0; s < 4; ++s)
      async16(aSrc[s] + aoff, &As_[buf][s * 4096 + wv * 1024]);
  };

  // ---- per-lane B read position bases: pbase[j] for output n = wn*96 + j*16 + col ----
  int pbase[6];
  for (int j = 0; j < 6; ++j) {
    int nl = wn * 96 + j * 16 + col;
    int hl = nl / W_, wl = nl % W_;
    pbase[j] = hl * 50 + wl;          // tap (dy,dx) reads pos pbase + dy*50 + dx
  }

  float4_t acc[4][6] = {};
  int q2 = quad * 2;

  // prologue: B chunk 0 + A (cc=0,tap=0) -> buf 0
  stageB(0);
  stageA(0, 0);
  int abuf = 0;

#pragma unroll 1
  for (int cc = 0; cc < 8; ++cc) {
#pragma unroll 1
    for (int tap = 0; tap < 9; ++tap) {
      // ---- acquire: stage(cur) landed, visible to all waves ----
      asm volatile("s_waitcnt vmcnt(0)\n\ts_barrier" ::: "memory");
      const unsigned char* A = As_[abuf];
      int dy = tap / 3, dx = tap - dy * 3;
      int doff = dy * 50 + dx;        // uniform
      int8v af[4], bfr[6];
      for (int i = 0; i < 4; ++i) {
        int r = wm * 64 + i * 16 + col;
        int rb = r * 128, x7 = r & 7;
        int4v lo = *(const int4v*)&A[rb + (((q2 + 0) ^ x7) << 4)];
        int4v hi = *(const int4v*)&A[rb + (((q2 + 1) ^ x7) << 4)];
        af[i] = (int8v){lo.x, lo.y, lo.z, lo.w, hi.x, hi.y, hi.z, hi.w};
      }
      for (int j = 0; j < 6; ++j) {
        int pj = pbase[j] + doff;
        int rb = pj << 7, x7 = pj & 7;
        int4v lo = *(const int4v*)&Bt[rb + (((q2 + 0) ^ x7) << 4)];
        int4v hi = *(const int4v*)&Bt[rb + (((q2 + 1) ^ x7) << 4)];
        bfr[j] = (int8v){lo.x, lo.y, lo.z, lo.w, hi.x, hi.y, hi.z, hi.w};
      }
      // ---- release: all waves' reads of A(abuf) (and, at tap 8, of Bt) complete ----
      asm volatile("s_waitcnt lgkmcnt(0)\n\ts_barrier" ::: "memory");
      __builtin_amdgcn_sched_barrier(0);
      // ---- prefetch next (flies under the MFMA cluster) ----
      int nt = tap + 1, ncc = cc;
      if (nt == 9) { nt = 0; ++ncc; }
      if (ncc < 8) {
        stageA(abuf ^ 1, nt * 1024 + ncc * 128);
        if (nt == 0) stageB(ncc);
      }
      __builtin_amdgcn_sched_barrier(0);
      __builtin_amdgcn_s_setprio(1);
      for (int i = 0; i < 4; ++i)
        for (int j = 0; j < 6; ++j)
          // A=W scaled by 2^9 -> e8m0 118 (2^-9); B=x scaled by 2^4 -> e8m0 123 (2^-4)
          acc[i][j] = __builtin_amdgcn_mfma_scale_f32_16x16x128_f8f6f4(
              af[i], bfr[j], acc[i][j], 0, 0, 0, 0x76767676, 0, 0x7B7B7B7B);
      __builtin_amdgcn_s_setprio(0);
      __builtin_amdgcn_sched_barrier(0);
      abuf ^= 1;
    }
  }

  // epilogue: bias + relu, store bf16 conv1[n*512 + m], 8B packed along m
  for (int i = 0; i < 4; ++i) {
    int mb = m0 + wm * 64 + i * 16 + quad * 4;
    float b0 = bias[mb + 0], b1 = bias[mb + 1], b2 = bias[mb + 2], b3 = bias[mb + 3];
    for (int j = 0; j < 6; ++j) {
      int n = n0 + wn * 96 + j * 16 + col;
      ushort4_t pk;
      pk.x = f2bf(fmaxf(acc[i][j].x + b0, 0.f));
      pk.y = f2bf(fmaxf(acc[i][j].y + b1, 0.f));
      pk.z = f2bf(fmaxf(acc[i][j].z + b2, 0.f));
      pk.w = f2bf(fmaxf(acc[i][j].w + b3, 0.f));
      *(ushort4_t*)&conv1[(long)n * 512 + mb] = pk;
    }
  }
}

// ------------- fused head GEMM + losses: [64 x 512] @ conv1^T + softmax/NLL + smooth-L1 --
// M=64 (54 used), N=24576, K=512. Tile 64(N) x BK=128. grid 384, 256 threads.
// v7: loss_fused is folded into the epilogue. The block holds all 54 m-channels for its
// 64 positions -> stage biased scores in LDS sacc[64][57] (57 coprime with 32: conflict-
// free rows), then (A) 2-way softmax over (a, a+9) -> prob + NLL, (B) bbox write +
// smooth-L1 accumulate. Kills cls_ws (4.4 MB rt), out_bbox re-read (3.5 MB), one launch.
// Values bit-identical to the separate-kernel path (same fp32 inputs to each formula).
__global__ __launch_bounds__(256, 2)
void head_gemm(const unsigned short* __restrict__ Wh, const unsigned short* __restrict__ conv1,
               const float* __restrict__ b_cls, const float* __restrict__ b_bbox,
               const int* __restrict__ label, const float* __restrict__ tgt,
               const float* __restrict__ iw, const float* __restrict__ ow,
               float* __restrict__ prob, float* __restrict__ out_bbox,
               float* __restrict__ accbuf) {
  __shared__ unsigned short As[64 * 128];   // 16 KB
  __shared__ unsigned short Bs[64 * 128];   // 16 KB
  __shared__ float sacc[64][57];            // 14.6 KB biased scores [n][m]
  __shared__ float red[12];
  int t = threadIdx.x;
  int lane = t & 63, wv = t >> 6;
  int n0 = blockIdx.x * 64;
  int quad = lane >> 4, col = lane & 15;
  const unsigned short* aS[4];
  const unsigned short* bS[4];
  for (int p = 0; p < 4; ++p) {
    int c = p * 256 + t;
    int r = c >> 4;
    int q = (c & 15) ^ (r & 15);
    aS[p] = Wh + (long)r * 512 + q * 8;
    bS[p] = conv1 + (long)(n0 + r) * 512 + q * 8;
  }
  float4_t acc[4] = {};
  for (int kt = 0; kt < 4; ++kt) {
    long koff = (long)kt * 128;
    __syncthreads();
    for (int p = 0; p < 4; ++p) async16(aS[p] + koff, &As[p * 2048 + wv * 512]);
    for (int p = 0; p < 4; ++p) async16(bS[p] + koff, &Bs[p * 2048 + wv * 512]);
    __syncthreads();
    for (int ks = 0; ks < 4; ++ks) {
      int rn = wv * 16 + col;
      bf16x8 bfr = *(const bf16x8*)&Bs[rn * 128 + (((ks * 4 + quad) ^ (rn & 15)) << 3)];
      for (int i = 0; i < 4; ++i) {
        int r = i * 16 + col;
        bf16x8 af = *(const bf16x8*)&As[r * 128 + (((ks * 4 + quad) ^ (r & 15)) << 3)];
        acc[i] = __builtin_amdgcn_mfma_f32_16x16x32_bf16(af, bfr, acc[i], 0, 0, 0);
      }
    }
  }
  // stage biased scores: thread holds m = i*16 + quad*4 + r for n-row (wv*16 + col)
  int nn_own = wv * 16 + col;
  for (int i = 0; i < 4; ++i) {
    for (int r = 0; r < 4; ++r) {
      int m = i * 16 + quad * 4 + r;
      if (m < 54) {
        float bv = (m < 18) ? b_cls[m] : b_bbox[m - 18];
        sacc[nn_own][m] = acc[i][r] + bv;
      }
    }
  }
  __syncthreads();

  int b = n0 / HW; int rem0 = n0 % HW;      // all 64 positions share batch b
  float nll = 0.f, val = 0.f, box = 0.f;
  // ---- phase A: 2-way softmax over (a, a+9), prob write + NLL (576 pairs) ----
  for (int p = t; p < 576; p += 256) {
    int a = p >> 6, nn = p & 63;
    float x0 = sacc[nn][a], x1 = sacc[nn][a + 9];
    float mx = fmaxf(x0, x1);
    float e0 = __expf(x0 - mx), e1 = __expf(x1 - mx);
    float s = e0 + e1;
    long i0 = (long)(b * 18 + a) * HW + rem0 + nn;
    prob[i0] = e0 / s;
    prob[i0 + (long)9 * HW] = e1 / s;
    int lb = label[b * 27648 + a * HW + rem0 + nn];
    if (lb != -1) {
      val += 1.f;
      float xl = (lb > 0) ? x1 : x0;
      nll -= (xl - mx - __logf(s));
    }
  }
  // ---- phase B: bbox write + smooth-L1 (2304 entries) ----
  for (int e = t; e < 2304; e += 256) {
    int mb = e >> 6, nn = e & 63;
    float v = sacc[nn][18 + mb];
    long g = (long)(b * 36 + mb) * HW + rem0 + nn;
    out_bbox[g] = v;
    float d = iw[g] * (v - tgt[g]);
    float ad = fabsf(d);
    float l = (ad < (1.f / 9.f)) ? d * d * 4.5f : ad - (1.f / 18.f);
    box += ow[g] * l;
  }
  // ---- block reduce + atomics ----
  nll = wave_sum(nll); val = wave_sum(val); box = wave_sum(box);
  if (lane == 0) { red[wv] = nll; red[4 + wv] = val; red[8 + wv] = box; }
  __syncthreads();
  if (t == 0) {
    atomicAdd(&accbuf[0], red[0] + red[1] + red[2] + red[3]);
    atomicAdd(&accbuf[1], red[4] + red[5] + red[6] + red[7]);
    atomicAdd(&accbuf[2], red[8] + red[9] + red[10] + red[11]);
  }
}

__global__ void finalize(const float* __restrict__ acc, float* __restrict__ out) {
  if (threadIdx.x == 0) {
    out[0] = acc[0] / fmaxf(acc[1], 1.f);
    out[1] = acc[2] / (float)B_;
  }
}

extern "C" void kernel_launch(void* const* d_in, const int* in_sizes, int n_in,
                              void* d_out, int out_size, void* d_ws, size_t ws_size,
                              hipStream_t stream) {
  const float* base_feat = (const float*)d_in[0];
  const float* W_conv    = (const float*)d_in[1];
  const float* b_conv    = (const float*)d_in[2];
  const float* W_cls     = (const float*)d_in[3];
  const float* b_cls     = (const float*)d_in[4];
  const float* W_bbox    = (const float*)d_in[5];
  const float* b_bbox    = (const float*)d_in[6];
  const int*   rpn_label = (const int*)d_in[7];
  const float* bb_tgt    = (const float*)d_in[8];
  const float* bb_iw     = (const float*)d_in[9];
  const float* bb_ow     = (const float*)d_in[10];

  float* out = (float*)d_out;
  float* out_cls_prob = out;                         // 442368
  float* out_bbox     = out + 442368;                // 884736
  float* out_scalars  = out + 442368 + 884736;       // 2

  // workspace layout
  size_t off = 0;
  auto alloc = [&](size_t bytes) {
    void* p = (char*)d_ws + off;
    off = (off + bytes + 255) & ~(size_t)255;
    return p;
  };
  const size_t XT_BYTES = (size_t)B_ * HP * WP * CIN;              // 27,033,600 (fp8)
  unsigned char*  xt    = (unsigned char*)alloc(XT_BYTES);
  unsigned char*  Wa    = (unsigned char*)alloc((size_t)OC * K9);
  unsigned short* conv1 = (unsigned short*)alloc((size_t)NPOS * OC * 2);
  unsigned short* Wh    = (unsigned short*)alloc((size_t)64 * 512 * 2);
  float* accbuf         = (float*)alloc(16);

  prep_fused<<<5168, 256, 0, stream>>>(base_feat, W_conv, W_cls, W_bbox, xt, Wa, Wh, accbuf);
  conv_gemm<<<dim3(128, 4), 256, 0, stream>>>(Wa, xt, b_conv, conv1);
  head_gemm<<<384, 256, 0, stream>>>(Wh, conv1, b_cls, b_bbox,
                                     rpn_label, bb_tgt, bb_iw, bb_ow,
                                     out_cls_prob, out_bbox, accbuf);
  finalize<<<1, 64, 0, stream>>>(accbuf, out_scalars);
}